// Round 17
// baseline (135.031 us; speedup 1.0000x reference)
//
#include <hip/hip_runtime.h>
#include <stdint.h>

#define DI __device__ __forceinline__

typedef __attribute__((ext_vector_type(4))) float f32x4;
typedef __attribute__((ext_vector_type(8))) short bf16x8;
typedef __attribute__((ext_vector_type(4))) short bf16x4;

// ---------------- workspace layout (bytes) ----------------
constexpr size_t OFF_FLAT  = 0;                               // 8192*4096 bf16 = 64MB
constexpr size_t OFF_TREPP = OFF_FLAT  + (size_t)8192*4096*2; // 16*4096*128 bf16 frags
constexpr size_t OFF_W1P   = OFF_TREPP + (size_t)16*4096*128*2; // 4*64*8 bf16
constexpr size_t OFF_W2P   = OFF_W1P   + 4096;                // 64 frags
constexpr size_t OFF_BOTP  = OFF_W2P   + 65536;               // 128 frags
constexpr size_t OFF_EXPB  = OFF_BOTP  + 131072;              // 4096*512 bf16
constexpr size_t OFF_WEBP  = OFF_EXPB  + (size_t)4096*512*2;  // 4096*128 bf16 frags = 1MB
constexpr size_t OFF_BEB   = OFF_WEBP  + (size_t)4096*128*2;  // 128 f32
constexpr size_t OFF_CNT   = OFF_BEB   + 512;
constexpr size_t OFF_CUR   = OFF_CNT   + 64;
constexpr size_t OFF_OFFS  = OFF_CUR   + 64;
constexpr size_t OFF_PERM  = OFF_OFFS  + 64;                  // 8192 int
constexpr size_t OFF_PART  = OFF_PERM  + 32768;               // 4*8192*256 f32 = 32MB
constexpr size_t PART_SZ   = (size_t)4 * 8192 * 256 * 4;
constexpr size_t WS_NEEDED = OFF_PART + PART_SZ;

DI unsigned short f2bf(float f) {
  union { float ff; unsigned int i; } v; v.ff = f;
  unsigned int x = v.i;
  return (unsigned short)((x + 0x7fffu + ((x >> 16) & 1u)) >> 16);  // RNE
}

DI unsigned cvtpk(float lo, float hi) {  // D[15:0]=bf16(lo), D[31:16]=bf16(hi), RNE
  unsigned r;
  asm("v_cvt_pk_bf16_f32 %0, %1, %2" : "=v"(r) : "v"(lo), "v"(hi));
  return r;
}

DI void gl_lds16(const void* g, void* lds) {
  __builtin_amdgcn_global_load_lds((const __attribute__((address_space(1))) void*)g,
                                   (__attribute__((address_space(3))) void*)lds, 16, 0, 0);
}

// ---------------- k_prep: small weight packs + exp_w cvt + task bucketing ----------------
// blocks [0,49): pack w2/bot/w1; [49,1073): cvt; 1073: bucket
__global__ __launch_bounds__(256) void k_prep(
    const float* __restrict__ conv2_w, const float* __restrict__ bot_w,
    const float* __restrict__ conv1_w,
    const float* __restrict__ exp_w,   const int* __restrict__ task,
    unsigned short* w2p, unsigned short* botp, unsigned short* w1p,
    unsigned short* expb, int* cnt, int* offs, int* perm)
{
  __shared__ int hh[16], oo[16];
  int bid = blockIdx.x, t = threadIdx.x;

  if (bid < 49) {                      // ---- pack w2 / bot / w1 ----
    int tid = bid * 256 + t;
    int g = tid >> 6, l = tid & 63;
    if (g >= 196) return;
    int lr = l & 15, chunk = l >> 4;
    if (g < 64) {                      // conv2_w as [512][64]
      int kt = g >> 2, nt = g & 3;
      int k0 = kt * 32 + chunk * 8, n = nt * 16 + lr;
      unsigned short v[8];
#pragma unroll
      for (int e = 0; e < 8; ++e) v[e] = f2bf(conv2_w[(size_t)(k0 + e) * 64 + n]);
      uint4 pk = { (unsigned)v[0] | ((unsigned)v[1] << 16), (unsigned)v[2] | ((unsigned)v[3] << 16),
                   (unsigned)v[4] | ((unsigned)v[5] << 16), (unsigned)v[6] | ((unsigned)v[7] << 16) };
      *(uint4*)(w2p + ((size_t)g * 64 + l) * 8) = pk;
    } else if (g < 192) {              // bot_w [512][128]
      int gl = g - 64;
      int kt = gl >> 3, nt = gl & 7;
      int k0 = kt * 32 + chunk * 8, n = nt * 16 + lr;
      unsigned short v[8];
#pragma unroll
      for (int e = 0; e < 8; ++e) v[e] = f2bf(bot_w[(size_t)(k0 + e) * 128 + n]);
      uint4 pk = { (unsigned)v[0] | ((unsigned)v[1] << 16), (unsigned)v[2] | ((unsigned)v[3] << 16),
                   (unsigned)v[4] | ((unsigned)v[5] << 16), (unsigned)v[6] | ((unsigned)v[7] << 16) };
      *(uint4*)(botp + ((size_t)gl * 64 + l) * 8) = pk;
    } else {                           // conv1 weights as A-frags, K=64 padded
      int gl = g - 192;
      int kt2 = gl >> 1, ct = gl & 1;
      int co = ct * 16 + lr;
      int ky = kt2 * 2 + (chunk >> 1);
      unsigned short v[8];
#pragma unroll
      for (int e = 0; e < 8; ++e) {
        int kx = (chunk & 1) * 2 + (e >> 2);
        int ci = e & 3;
        v[e] = (ci < 3) ? f2bf(conv1_w[((ky * 4 + kx) * 3 + ci) * 32 + co]) : (unsigned short)0;
      }
      uint4 pk = { (unsigned)v[0] | ((unsigned)v[1] << 16), (unsigned)v[2] | ((unsigned)v[3] << 16),
                   (unsigned)v[4] | ((unsigned)v[5] << 16), (unsigned)v[6] | ((unsigned)v[7] << 16) };
      *(uint4*)(w1p + ((size_t)gl * 64 + l) * 8) = pk;
    }
  } else if (bid < 1073) {             // ---- cvt: exp_w fp32 -> bf16 ----
    int i = (bid - 49) * 256 + t;      // 262144 total, 8 elems each
    f32x4 a = *(const f32x4*)(exp_w + (size_t)i * 8);
    f32x4 b = *(const f32x4*)(exp_w + (size_t)i * 8 + 4);
    uint4 pk = { (unsigned)f2bf(a[0]) | ((unsigned)f2bf(a[1]) << 16), (unsigned)f2bf(a[2]) | ((unsigned)f2bf(a[3]) << 16),
                 (unsigned)f2bf(b[0]) | ((unsigned)f2bf(b[1]) << 16), (unsigned)f2bf(b[2]) | ((unsigned)f2bf(b[3]) << 16) };
    *(uint4*)(expb + (size_t)i * 8) = pk;
  } else {                             // ---- bucket: histogram + scan + scatter (1 block) ----
    if (t < 16) hh[t] = 0;
    __syncthreads();
    int my[32];
#pragma unroll
    for (int i = 0; i < 32; ++i) { my[i] = task[t * 32 + i]; atomicAdd(&hh[my[i]], 1); }
    __syncthreads();
    if (t == 0) {
      int off = 0;
      for (int i = 0; i < 16; ++i) { oo[i] = off; offs[i] = off; cnt[i] = hh[i]; off += hh[i]; }
    }
    __syncthreads();
#pragma unroll
    for (int i = 0; i < 32; ++i) { int slot = atomicAdd(&oo[my[i]], 1); perm[slot] = t * 32 + i; }
  }
}

// ---------------- k_convx: conv(8192) + trep-pack(4096) + wfuse(128) + beb(1) merged ----------------
__global__ __launch_bounds__(256) void k_convx(
    const float* __restrict__ x, const unsigned short* __restrict__ w1p, const float* __restrict__ b1,
    const unsigned short* __restrict__ w2p, const float* __restrict__ b2,
    unsigned short* __restrict__ flat,
    const float* __restrict__ trep_w, unsigned short* __restrict__ trepp,
    const unsigned short* __restrict__ expb, const unsigned short* __restrict__ botp,
    unsigned short* __restrict__ webp,
    const float* __restrict__ exp_b, const float* __restrict__ bot_w, const float* __restrict__ bot_b,
    float* __restrict__ beb)
{
  __shared__ __align__(16) unsigned short h1p[18 * 18 * 32]; // conv: padded h1 bf16, swizzled
  __shared__ __align__(16) unsigned short xpad[1304];        // conv: [18][18][4ch] bf16
  __shared__ __align__(16) unsigned short Asm[64 * 64];      // wfuse: 8KB
  __shared__ float red2[2][128];                             // beb
  int bid = blockIdx.x;
  int t = threadIdx.x, l = t & 63, w = t >> 6;
  int lr = l & 15, cg = l >> 4;

  if (bid < 8192) {                    // ---- conv (r9/r14 proven body) ----
    int img = bid;
    for (int i = t; i < 1296; i += 256) ((uint4*)h1p)[i] = uint4{0, 0, 0, 0};
    if (t < 163) ((uint4*)xpad)[t] = uint4{0, 0, 0, 0};

    bf16x8 w1a[4];
#pragma unroll
    for (int i = 0; i < 4; ++i) w1a[i] = *(const bf16x8*)(w1p + ((size_t)i * 64 + l) * 8);
    f32x4 b1v0 = *(const f32x4*)(b1 + cg * 4);
    f32x4 b1v1 = *(const f32x4*)(b1 + 16 + cg * 4);

    __syncthreads();
    {
      const float* xs = x + ((size_t)img * 256 + t) * 3;
      float v0 = xs[0], v1 = xs[1], v2 = xs[2];
      uint2 pk;
      pk.x = cvtpk(v0, v1);
      pk.y = cvtpk(v2, 0.f);
      int py = t >> 4, px = t & 15;
      *(uint2*)&xpad[((py + 1) * 18 + (px + 1)) * 4] = pk;
    }
    __syncthreads();

    for (int oi = 0; oi < 4; ++oi) {
      int oy = w + oi * 4;
      if (oy > 14) break;
      f32x4 a0 = b1v0, a1 = b1v1;
#pragma unroll
      for (int kt2 = 0; kt2 < 2; ++kt2) {
        int row = oy + kt2 * 2 + (cg >> 1);
        int c0 = lr + (cg & 1) * 2;
        union { bf16x4 h[2]; bf16x8 v; } u;
        u.h[0] = *(const bf16x4*)&xpad[(row * 18 + c0) * 4];
        u.h[1] = *(const bf16x4*)&xpad[(row * 18 + c0 + 1) * 4];
        a0 = __builtin_amdgcn_mfma_f32_16x16x32_bf16(w1a[kt2 * 2 + 0], u.v, a0, 0, 0, 0);
        a1 = __builtin_amdgcn_mfma_f32_16x16x32_bf16(w1a[kt2 * 2 + 1], u.v, a1, 0, 0, 0);
      }
      if (lr < 15) {
        int row2 = oy + 2, col2 = lr + 2;
        int h = (((row2 >> 1) & 1) << 2) | ((col2 >> 1) & 3);
        int pixbase = (row2 * 18 + col2) * 32;
        int off = (cg & 1) * 4;
        {
          uint2 pk;
          pk.x = cvtpk(fmaxf(a0[0], 0.f), fmaxf(a0[1], 0.f));
          pk.y = cvtpk(fmaxf(a0[2], 0.f), fmaxf(a0[3], 0.f));
          int g8 = (cg >> 1);
          *(uint2*)&h1p[pixbase + ((g8 ^ h) << 3) + off] = pk;
        }
        {
          uint2 pk;
          pk.x = cvtpk(fmaxf(a1[0], 0.f), fmaxf(a1[1], 0.f));
          pk.y = cvtpk(fmaxf(a1[2], 0.f), fmaxf(a1[3], 0.f));
          int g8 = 2 + (cg >> 1);
          *(uint2*)&h1p[pixbase + ((g8 ^ h) << 3) + off] = pk;
        }
      }
    }
    __syncthreads();

    int wm = w >> 1, wn = w & 1;
    int ox2 = lr & 7;
    f32x4 acc2[2][2] = {};
#pragma unroll
    for (int q = 0; q < 4; ++q) {
      int kyh = q >> 1, kxh = q & 1;
      bf16x8 bq[2][4];
#pragma unroll
      for (int ntl = 0; ntl < 2; ++ntl)
#pragma unroll
        for (int kk = 0; kk < 4; ++kk) {
          int kt = (2 * kyh + (kk >> 1)) * 4 + 2 * kxh + (kk & 1);
          bq[ntl][kk] = *(const bf16x8*)(w2p + ((size_t)(kt * 4 + wn * 2 + ntl) * 64 + l) * 8);
        }
#pragma unroll
      for (int mtl = 0; mtl < 2; ++mtl) {
        int oy2 = (wm * 2 + mtl) * 2 + (lr >> 3);
        int ry = oy2 + kyh, rx = ox2 + kxh;
        int h = ((ry & 1) << 2) | (rx & 3);
        const unsigned short* ap = h1p + ((ry * 2) * 18 + rx * 2) * 32 + ((cg ^ h) << 3);
        bf16x8 a00 = *(const bf16x8*)(ap);
        bf16x8 a01 = *(const bf16x8*)(ap + 32);
        bf16x8 a10 = *(const bf16x8*)(ap + 576);
        bf16x8 a11 = *(const bf16x8*)(ap + 608);
#pragma unroll
        for (int ntl = 0; ntl < 2; ++ntl) {
          acc2[mtl][ntl] = __builtin_amdgcn_mfma_f32_16x16x32_bf16(a00, bq[ntl][0], acc2[mtl][ntl], 0, 0, 0);
          acc2[mtl][ntl] = __builtin_amdgcn_mfma_f32_16x16x32_bf16(a01, bq[ntl][1], acc2[mtl][ntl], 0, 0, 0);
          acc2[mtl][ntl] = __builtin_amdgcn_mfma_f32_16x16x32_bf16(a10, bq[ntl][2], acc2[mtl][ntl], 0, 0, 0);
          acc2[mtl][ntl] = __builtin_amdgcn_mfma_f32_16x16x32_bf16(a11, bq[ntl][3], acc2[mtl][ntl], 0, 0, 0);
        }
      }
    }
    unsigned short* fr = flat + (size_t)img * 4096;
#pragma unroll
    for (int ntl = 0; ntl < 2; ++ntl) {
      int co = (wn * 2 + ntl) * 16 + lr;
      float bias2 = b2[co];
#pragma unroll
      for (int mtl = 0; mtl < 2; ++mtl)
#pragma unroll
        for (int r = 0; r < 4; ++r) {
          int pix = (wm * 2 + mtl) * 16 + cg * 4 + r;
          fr[pix * 64 + co] = f2bf(fmaxf(acc2[mtl][ntl][r] + bias2, 0.f));
        }
    }
  } else if (bid < 12288) {            // ---- trep pack: [16][4096][128] -> B-frags ----
    int tid = (bid - 8192) * 256 + t;  // 16384 groups x 64 lanes
    int gl = tid >> 6, l2 = tid & 63;
    int lr2 = l2 & 15, chunk = l2 >> 4;
    int tk = gl >> 10, rem = gl & 1023;
    int kt = rem >> 3, nt = rem & 7;
    const float* src = trep_w + (size_t)tk * 4096 * 128;
    int k0 = kt * 32 + chunk * 8, n = nt * 16 + lr2;
    unsigned short v[8];
#pragma unroll
    for (int e = 0; e < 8; ++e) v[e] = f2bf(src[(size_t)(k0 + e) * 128 + n]);
    uint4 pk = { (unsigned)v[0] | ((unsigned)v[1] << 16), (unsigned)v[2] | ((unsigned)v[3] << 16),
                 (unsigned)v[4] | ((unsigned)v[5] << 16), (unsigned)v[6] | ((unsigned)v[7] << 16) };
    *(uint4*)(trepp + (size_t)tk * 524288 + ((size_t)rem * 64 + l2) * 8) = pk;
  } else if (bid < 12416) {            // ---- wfuse: W_eb = exp_w @ bot_w -> B-frag ----
    int wb = bid - 12288;
    int nb = wb & 1, mb = wb >> 1;     // mb 0..63
    int wm = w >> 1, wn = w & 1;
    int cig = l >> 4;
    f32x4 acc[2][2] = {};
    for (int ktb = 0; ktb < 8; ++ktb) {
      __syncthreads();
#pragma unroll
      for (int jj = 0; jj < 2; ++jj) {
        int q = w * 128 + jj * 64 + l;
        int row = q >> 3, p = q & 7;
        const unsigned short* g = expb + (size_t)(mb * 64 + row) * 512 + ktb * 64 + ((p ^ (row & 7)) * 8);
        gl_lds16(g, (char*)Asm + (w * 128 + jj * 64) * 16);
      }
      __syncthreads();
#pragma unroll
      for (int k32 = 0; k32 < 2; ++k32) {
        bf16x8 af[2];
#pragma unroll
        for (int mf = 0; mf < 2; ++mf) {
          int row = wm * 32 + mf * 16 + lr;
          int c = k32 * 4 + cig;
          af[mf] = *(const bf16x8*)(Asm + row * 64 + ((c ^ (row & 7)) * 8));
        }
#pragma unroll
        for (int nf = 0; nf < 2; ++nf) {
          int ntg = nb * 4 + wn * 2 + nf;
          bf16x8 bf = *(const bf16x8*)(botp + ((size_t)((ktb * 2 + k32) * 8 + ntg) * 64 + l) * 8);
#pragma unroll
          for (int mf = 0; mf < 2; ++mf)
            acc[mf][nf] = __builtin_amdgcn_mfma_f32_16x16x32_bf16(af[mf], bf, acc[mf][nf], 0, 0, 0);
        }
      }
    }
#pragma unroll
    for (int nf = 0; nf < 2; ++nf) {
      int n = nb * 64 + (wn * 2 + nf) * 16 + lr;
#pragma unroll
      for (int mf = 0; mf < 2; ++mf) {
        int rowb = mb * 64 + wm * 32 + mf * 16 + (l >> 4) * 4;
#pragma unroll
        for (int r = 0; r < 4; ++r) {
          int row = rowb + r;               // K-index of W_eb
          int ktn = row >> 5, rr = row & 31;
          int l2 = (rr >> 3) * 16 + (n & 15);
          webp[((size_t)(ktn * 8 + (n >> 4)) * 64 + l2) * 8 + (rr & 7)] = f2bf(acc[mf][nf][r]);
        }
      }
    }
  } else {                             // ---- beb = exp_b @ bot_w + bot_b ----
    int n = t & 127, js = t >> 7;      // js in [0,2): j-chunk of 256
    float s = 0.f;
    for (int j = js * 256; j < js * 256 + 256; ++j)
      s += exp_b[j] * bot_w[j * 128 + n];
    red2[js][n] = s;
    __syncthreads();
    if (t < 128) beb[t] = bot_b[t] + (red2[0][t] + red2[1][t]);
  }
}

// ---------------- K-split grouped GEMM, M=128, K-split 4, single-buffer 2-barrier ----------------
// blockIdx: x = m-tile (0..7, 128 rows each), y = task (0..15), z = k-slice (0..3; 1024 K each)
__global__ __launch_bounds__(512) void k_task6(
    const unsigned short* __restrict__ flat, const unsigned short* __restrict__ trepp,
    const unsigned short* __restrict__ webp,
    const int* __restrict__ cnt, const int* __restrict__ offs, const int* __restrict__ perm,
    float* __restrict__ part)
{
  __shared__ __align__(16) unsigned short Asm[128 * 64];   // 16KB, XOR-swizzled
  __shared__ __align__(16) unsigned short Bsm[8192];       // 16KB trep frags
  __shared__ __align__(16) unsigned short Wsm[8192];       // 16KB W_eb frags
  __shared__ int prow[128];
  int t = threadIdx.x, l = t & 63, w = t >> 6;
  int mt = blockIdx.x, task = blockIdx.y, ks = blockIdx.z;
  int count = cnt[task];
  int r0 = mt * 128;
  if (r0 >= count) return;
  int nrows = count - r0; if (nrows > 128) nrows = 128;
  int base = offs[task];
  if (t < 128) { int rr = t < nrows ? t : (nrows - 1); prow[t] = perm[base + r0 + rr]; }
  __syncthreads();
  int lr = l & 15, cig = l >> 4;
  f32x4 atr[8] = {}, ash[8] = {};
  const unsigned short* Bt = trepp + (size_t)task * 524288;

  for (int it = 0; it < 16; ++it) {
    int ktb = ks * 16 + it;
    __syncthreads();
#pragma unroll
    for (int ii = 0; ii < 2; ++ii) {
      int c = ii * 512 + t;
      int row = c >> 3, s = c & 7;
      const unsigned short* g = flat + (size_t)prow[row] * 4096 + ktb * 64 + ((s ^ (row & 7)) * 8);
      gl_lds16(g, (char*)Asm + (ii * 512 + w * 64) * 16);
    }
#pragma unroll
    for (int ii = 0; ii < 2; ++ii) {
      int c = ii * 512 + t;
      gl_lds16(Bt + (size_t)ktb * 8192 + c * 8, (char*)Bsm + (ii * 512 + w * 64) * 16);
      gl_lds16(webp + (size_t)ktb * 8192 + c * 8, (char*)Wsm + (ii * 512 + w * 64) * 16);
    }
    __syncthreads();
    int arow = w * 16 + lr;
#pragma unroll
    for (int k32 = 0; k32 < 2; ++k32) {
      bf16x8 af = *(const bf16x8*)(Asm + arow * 64 + (((k32 * 4 + cig) ^ (arow & 7)) * 8));
      const unsigned short* bs = Bsm + k32 * 4096;
      const unsigned short* ws = Wsm + k32 * 4096;
#pragma unroll
      for (int nf = 0; nf < 8; ++nf) {
        bf16x8 bf = *(const bf16x8*)(bs + (nf * 64 + l) * 8);
        atr[nf] = __builtin_amdgcn_mfma_f32_16x16x32_bf16(af, bf, atr[nf], 0, 0, 0);
        bf16x8 wf = *(const bf16x8*)(ws + (nf * 64 + l) * 8);
        ash[nf] = __builtin_amdgcn_mfma_f32_16x16x32_bf16(af, wf, ash[nf], 0, 0, 0);
      }
    }
  }

  // write fp32 partials: part[ks][base + r0 + r_loc][n(0-127=shared,128-255=trep)]
  size_t gb = (size_t)ks * 8192 + base + r0;
#pragma unroll
  for (int nf = 0; nf < 8; ++nf) {
    int n = nf * 16 + lr;
#pragma unroll
    for (int r = 0; r < 4; ++r) {
      int r_loc = w * 16 + cig * 4 + r;
      if (r_loc < nrows) {
        float* p = part + (gb + r_loc) * 256;
        p[n] = ash[nf][r];
        p[128 + n] = atr[nf][r];
      }
    }
  }
}

// ---------------- epilogue: sum 4 slices, bias+relu, head, scatter ----------------
__global__ __launch_bounds__(256) void k_fin(
    const float* __restrict__ part,
    const int* __restrict__ perm, const int* __restrict__ task,
    const float* __restrict__ trep_b, const float* __restrict__ b_eb,
    const float* __restrict__ thead_w, const float* __restrict__ thead_b,
    float* __restrict__ out)
{
  __shared__ float sm[32 * 260];
  __shared__ int tsk[32], orow[32];
  int t = threadIdx.x;
  int g0 = blockIdx.x * 32;
  if (t < 32) {
    int orig = perm[g0 + t];
    orow[t] = orig;
    tsk[t] = task[orig];
  }
  __syncthreads();
  // phase 1: sum 4 slices, bias+relu -> sm
  for (int i = t; i < 32 * 64; i += 256) {
    int r = i >> 6, c4 = (i & 63) * 4;
    f32x4 s = {};
#pragma unroll
    for (int sl = 0; sl < 4; ++sl)
      s += *(const f32x4*)(part + ((size_t)sl * 8192 + g0 + r) * 256 + c4);
    f32x4 bv;
    if (c4 < 128) bv = *(const f32x4*)(b_eb + c4);
    else bv = *(const f32x4*)(trep_b + tsk[r] * 128 + (c4 - 128));
    s += bv;
    s = f32x4{fmaxf(s[0], 0.f), fmaxf(s[1], 0.f), fmaxf(s[2], 0.f), fmaxf(s[3], 0.f)};
    *(f32x4*)(sm + r * 260 + c4) = s;
  }
  __syncthreads();
  // phase 2: head (128 active threads: 32 rows x 4 actions)
  if (t < 128) {
    int r = t >> 2, a = t & 3;
    int tk = tsk[r];
    const float* thw = thead_w + (size_t)tk * 1024;
    float q = thead_b[tk * 4 + a];
    for (int c = 0; c < 256; ++c) q += sm[r * 260 + c] * thw[c * 4 + a];
    out[(size_t)orow[r] * 4 + a] = q;
  }
}

// ---------------- fallback fused grouped GEMM (small-ws path) ----------------
__global__ __launch_bounds__(256) void k_task2(
    const unsigned short* __restrict__ flat, const unsigned short* __restrict__ trepp,
    const unsigned short* __restrict__ webp,
    const float* __restrict__ trep_b, const float* __restrict__ b_eb,
    const float* __restrict__ thead_w, const float* __restrict__ thead_b,
    const int* __restrict__ cnt, const int* __restrict__ offs, const int* __restrict__ perm,
    float* __restrict__ out)
{
  __shared__ __align__(16) unsigned short Asm[64 * 64];
  __shared__ __align__(16) unsigned short Bsm[2 * 8 * 64 * 8];
  __shared__ __align__(16) unsigned short Wsm[2 * 8 * 64 * 8];
  __shared__ int prow[64];
  int t = threadIdx.x, l = t & 63, w = t >> 6;
  int task = blockIdx.x >> 7, mt = blockIdx.x & 127;
  int count = cnt[task];
  int r0 = mt * 64;
  if (r0 >= count) return;
  int nrows = count - r0; if (nrows > 64) nrows = 64;
  int base = offs[task];
  if (t < 64) { int rr = t < nrows ? t : (nrows - 1); prow[t] = perm[base + r0 + rr]; }
  __syncthreads();
  int lr = l & 15, cig = l >> 4;
  f32x4 atr[8] = {}, ash[8] = {};
  const unsigned short* Bt = trepp + (size_t)task * 524288;

  for (int ktb = 0; ktb < 64; ++ktb) {
    __syncthreads();
#pragma unroll
    for (int ii = 0; ii < 2; ++ii) {
      int c = ii * 256 + w * 64 + l;
      int row = c >> 3, s = c & 7;
      const unsigned short* g = flat + (size_t)prow[row] * 4096 + ktb * 64 + ((s ^ (row & 7)) * 8);
      gl_lds16(g, (char*)Asm + (ii * 256 + w * 64) * 16);
    }
#pragma unroll
    for (int ii = 0; ii < 4; ++ii) {
      int c = ii * 256 + w * 64 + l;
      gl_lds16(Bt + (size_t)ktb * 8192 + c * 8, (char*)Bsm + (ii * 256 + w * 64) * 16);
      gl_lds16(webp + (size_t)ktb * 8192 + c * 8, (char*)Wsm + (ii * 256 + w * 64) * 16);
    }
    __syncthreads();
    int arow = w * 16 + lr;
#pragma unroll
    for (int k32 = 0; k32 < 2; ++k32) {
      bf16x8 af = *(const bf16x8*)(Asm + arow * 64 + (((k32 * 4 + cig) ^ (arow & 7)) * 8));
      const unsigned short* bs = Bsm + k32 * 4096;
      const unsigned short* ws = Wsm + k32 * 4096;
#pragma unroll
      for (int nf = 0; nf < 8; ++nf) {
        bf16x8 bf = *(const bf16x8*)(bs + (nf * 64 + l) * 8);
        atr[nf] = __builtin_amdgcn_mfma_f32_16x16x32_bf16(af, bf, atr[nf], 0, 0, 0);
        bf16x8 wf = *(const bf16x8*)(ws + (nf * 64 + l) * 8);
        ash[nf] = __builtin_amdgcn_mfma_f32_16x16x32_bf16(af, wf, ash[nf], 0, 0, 0);
      }
    }
  }

  const float* thw = thead_w + (size_t)task * 1024;
  f32x4 qp[4] = {};
#pragma unroll
  for (int nf = 0; nf < 8; ++nf) {
    int n = nf * 16 + lr;
    float tb = trep_b[task * 128 + n];
    float bb = b_eb[n];
    f32x4 wsh = *(const f32x4*)(thw + n * 4);
    f32x4 wtr = *(const f32x4*)(thw + (128 + n) * 4);
#pragma unroll
    for (int r = 0; r < 4; ++r) {
      float sh = fmaxf(ash[nf][r] + bb, 0.f);
      float tr = fmaxf(atr[nf][r] + tb, 0.f);
      qp[r] += sh * wsh + tr * wtr;
    }
  }
#pragma unroll
  for (int m = 1; m < 16; m <<= 1)
#pragma unroll
    for (int r = 0; r < 4; ++r)
#pragma unroll
      for (int c2 = 0; c2 < 4; ++c2)
        qp[r][c2] += __shfl_xor(qp[r][c2], m, 64);

  if (lr < 4) {
    int rloc = w * 16 + cig * 4 + lr;
    if (rloc < nrows) {
      f32x4 q = qp[lr];
      f32x4 tb4 = *(const f32x4*)(thead_b + task * 4);
      q += tb4;
      *(f32x4*)(out + (size_t)prow[rloc] * 4) = q;
    }
  }
}

// ---------------- launcher ----------------
extern "C" void kernel_launch(void* const* d_in, const int* in_sizes, int n_in,
                              void* d_out, int out_size, void* d_ws, size_t ws_size,
                              hipStream_t stream)
{
  const float* x    = (const float*)d_in[0];
  const int*   task = (const int*)d_in[1];
  const float* c1w  = (const float*)d_in[2];
  const float* c1b  = (const float*)d_in[3];
  const float* c2w  = (const float*)d_in[4];
  const float* c2b  = (const float*)d_in[5];
  const float* expw = (const float*)d_in[6];
  const float* expb_bias = (const float*)d_in[7];
  const float* botw = (const float*)d_in[8];
  const float* botb = (const float*)d_in[9];
  const float* trw  = (const float*)d_in[10];
  const float* trb  = (const float*)d_in[11];
  const float* thw  = (const float*)d_in[12];
  const float* thb  = (const float*)d_in[13];
  float* out = (float*)d_out;
  char* ws = (char*)d_ws;

  unsigned short* flat  = (unsigned short*)(ws + OFF_FLAT);
  unsigned short* trepp = (unsigned short*)(ws + OFF_TREPP);
  unsigned short* w1p   = (unsigned short*)(ws + OFF_W1P);
  unsigned short* w2p   = (unsigned short*)(ws + OFF_W2P);
  unsigned short* botp  = (unsigned short*)(ws + OFF_BOTP);
  unsigned short* expb  = (unsigned short*)(ws + OFF_EXPB);
  unsigned short* webp  = (unsigned short*)(ws + OFF_WEBP);
  float* beb  = (float*)(ws + OFF_BEB);
  int* cnt    = (int*)(ws + OFF_CNT);
  int* offs   = (int*)(ws + OFF_OFFS);
  int* perm   = (int*)(ws + OFF_PERM);
  float* part = (float*)(ws + OFF_PART);

  k_prep<<<1074, 256, 0, stream>>>(c2w, botw, c1w, expw, task,
                                   w2p, botp, w1p, expb, cnt, offs, perm);
  k_convx<<<12417, 256, 0, stream>>>(x, w1p, c1b, w2p, c2b, flat,
                                     trw, trepp,
                                     expb, botp, webp, expb_bias, botw, botb, beb);
  if (ws_size >= WS_NEEDED) {
    k_task6<<<dim3(8, 16, 4), 512, 0, stream>>>(flat, trepp, webp, cnt, offs, perm, part);
    k_fin<<<256, 256, 0, stream>>>(part, perm, task, trb, beb, thw, thb, out);
  } else {
    k_task2<<<2048, 256, 0, stream>>>(flat, trepp, webp, trb, beb, thw, thb, cnt, offs, perm, out);
  }
}

// Round 18
// 131.117 us; speedup vs baseline: 1.0298x; 1.0298x over previous
//
#include <hip/hip_runtime.h>
#include <stdint.h>

#define DI __device__ __forceinline__

typedef __attribute__((ext_vector_type(4))) float f32x4;
typedef __attribute__((ext_vector_type(8))) short bf16x8;
typedef __attribute__((ext_vector_type(4))) short bf16x4;

// ---------------- workspace layout (bytes) ----------------
constexpr size_t OFF_FLAT  = 0;                               // 8192*4096 bf16 = 64MB
constexpr size_t OFF_TREPP = OFF_FLAT  + (size_t)8192*4096*2; // 16*4096*128 bf16 frags
constexpr size_t OFF_W1P   = OFF_TREPP + (size_t)16*4096*128*2; // 4*64*8 bf16
constexpr size_t OFF_W2P   = OFF_W1P   + 4096;                // 64 frags
constexpr size_t OFF_BOTP  = OFF_W2P   + 65536;               // 128 frags
constexpr size_t OFF_EXPB  = OFF_BOTP  + 131072;              // 4096*512 bf16
constexpr size_t OFF_WEBP  = OFF_EXPB  + (size_t)4096*512*2;  // 4096*128 bf16 frags = 1MB
constexpr size_t OFF_BEB   = OFF_WEBP  + (size_t)4096*128*2;  // 128 f32
constexpr size_t OFF_CNT   = OFF_BEB   + 512;
constexpr size_t OFF_CUR   = OFF_CNT   + 64;
constexpr size_t OFF_OFFS  = OFF_CUR   + 64;
constexpr size_t OFF_PERM  = OFF_OFFS  + 64;                  // 8192 int
constexpr size_t OFF_PART  = OFF_PERM  + 32768;               // 4*8192*256 f32 = 32MB
constexpr size_t PART_SZ   = (size_t)4 * 8192 * 256 * 4;
constexpr size_t WS_NEEDED = OFF_PART + PART_SZ;

DI unsigned short f2bf(float f) {
  union { float ff; unsigned int i; } v; v.ff = f;
  unsigned int x = v.i;
  return (unsigned short)((x + 0x7fffu + ((x >> 16) & 1u)) >> 16);  // RNE
}

DI unsigned cvtpk(float lo, float hi) {  // D[15:0]=bf16(lo), D[31:16]=bf16(hi), RNE
  unsigned r;
  asm("v_cvt_pk_bf16_f32 %0, %1, %2" : "=v"(r) : "v"(lo), "v"(hi));
  return r;
}

DI void gl_lds16(const void* g, void* lds) {
  __builtin_amdgcn_global_load_lds((const __attribute__((address_space(1))) void*)g,
                                   (__attribute__((address_space(3))) void*)lds, 16, 0, 0);
}

// ---------------- k_prep: small weight packs + exp_w cvt + task bucketing ----------------
// blocks [0,49): pack w2/bot/w1; [49,1073): cvt; 1073: bucket
__global__ __launch_bounds__(256) void k_prep(
    const float* __restrict__ conv2_w, const float* __restrict__ bot_w,
    const float* __restrict__ conv1_w,
    const float* __restrict__ exp_w,   const int* __restrict__ task,
    unsigned short* w2p, unsigned short* botp, unsigned short* w1p,
    unsigned short* expb, int* cnt, int* offs, int* perm)
{
  __shared__ int hh[16], oo[16];
  int bid = blockIdx.x, t = threadIdx.x;

  if (bid < 49) {                      // ---- pack w2 / bot / w1 ----
    int tid = bid * 256 + t;
    int g = tid >> 6, l = tid & 63;
    if (g >= 196) return;
    int lr = l & 15, chunk = l >> 4;
    if (g < 64) {                      // conv2_w as [512][64]
      int kt = g >> 2, nt = g & 3;
      int k0 = kt * 32 + chunk * 8, n = nt * 16 + lr;
      unsigned short v[8];
#pragma unroll
      for (int e = 0; e < 8; ++e) v[e] = f2bf(conv2_w[(size_t)(k0 + e) * 64 + n]);
      uint4 pk = { (unsigned)v[0] | ((unsigned)v[1] << 16), (unsigned)v[2] | ((unsigned)v[3] << 16),
                   (unsigned)v[4] | ((unsigned)v[5] << 16), (unsigned)v[6] | ((unsigned)v[7] << 16) };
      *(uint4*)(w2p + ((size_t)g * 64 + l) * 8) = pk;
    } else if (g < 192) {              // bot_w [512][128]
      int gl = g - 64;
      int kt = gl >> 3, nt = gl & 7;
      int k0 = kt * 32 + chunk * 8, n = nt * 16 + lr;
      unsigned short v[8];
#pragma unroll
      for (int e = 0; e < 8; ++e) v[e] = f2bf(bot_w[(size_t)(k0 + e) * 128 + n]);
      uint4 pk = { (unsigned)v[0] | ((unsigned)v[1] << 16), (unsigned)v[2] | ((unsigned)v[3] << 16),
                   (unsigned)v[4] | ((unsigned)v[5] << 16), (unsigned)v[6] | ((unsigned)v[7] << 16) };
      *(uint4*)(botp + ((size_t)gl * 64 + l) * 8) = pk;
    } else {                           // conv1 weights as A-frags, K=64 padded
      int gl = g - 192;
      int kt2 = gl >> 1, ct = gl & 1;
      int co = ct * 16 + lr;
      int ky = kt2 * 2 + (chunk >> 1);
      unsigned short v[8];
#pragma unroll
      for (int e = 0; e < 8; ++e) {
        int kx = (chunk & 1) * 2 + (e >> 2);
        int ci = e & 3;
        v[e] = (ci < 3) ? f2bf(conv1_w[((ky * 4 + kx) * 3 + ci) * 32 + co]) : (unsigned short)0;
      }
      uint4 pk = { (unsigned)v[0] | ((unsigned)v[1] << 16), (unsigned)v[2] | ((unsigned)v[3] << 16),
                   (unsigned)v[4] | ((unsigned)v[5] << 16), (unsigned)v[6] | ((unsigned)v[7] << 16) };
      *(uint4*)(w1p + ((size_t)gl * 64 + l) * 8) = pk;
    }
  } else if (bid < 1073) {             // ---- cvt: exp_w fp32 -> bf16 ----
    int i = (bid - 49) * 256 + t;      // 262144 total, 8 elems each
    f32x4 a = *(const f32x4*)(exp_w + (size_t)i * 8);
    f32x4 b = *(const f32x4*)(exp_w + (size_t)i * 8 + 4);
    uint4 pk = { (unsigned)f2bf(a[0]) | ((unsigned)f2bf(a[1]) << 16), (unsigned)f2bf(a[2]) | ((unsigned)f2bf(a[3]) << 16),
                 (unsigned)f2bf(b[0]) | ((unsigned)f2bf(b[1]) << 16), (unsigned)f2bf(b[2]) | ((unsigned)f2bf(b[3]) << 16) };
    *(uint4*)(expb + (size_t)i * 8) = pk;
  } else {                             // ---- bucket: histogram + scan + scatter (1 block) ----
    if (t < 16) hh[t] = 0;
    __syncthreads();
    int my[32];
#pragma unroll
    for (int i = 0; i < 32; ++i) { my[i] = task[t * 32 + i]; atomicAdd(&hh[my[i]], 1); }
    __syncthreads();
    if (t == 0) {
      int off = 0;
      for (int i = 0; i < 16; ++i) { oo[i] = off; offs[i] = off; cnt[i] = hh[i]; off += hh[i]; }
    }
    __syncthreads();
#pragma unroll
    for (int i = 0; i < 32; ++i) { int slot = atomicAdd(&oo[my[i]], 1); perm[slot] = t * 32 + i; }
  }
}

// ---------------- k_convx: interleaved conv(8192)+trep-pack(4096) + wfuse(128) + beb(1) ----------------
// blocks [0,12288): groups of 3 = {2 conv, 1 trep} for co-residency overlap
__global__ __launch_bounds__(256) void k_convx(
    const float* __restrict__ x, const unsigned short* __restrict__ w1p, const float* __restrict__ b1,
    const unsigned short* __restrict__ w2p, const float* __restrict__ b2,
    unsigned short* __restrict__ flat,
    const float* __restrict__ trep_w, unsigned short* __restrict__ trepp,
    const unsigned short* __restrict__ expb, const unsigned short* __restrict__ botp,
    unsigned short* __restrict__ webp,
    const float* __restrict__ exp_b, const float* __restrict__ bot_w, const float* __restrict__ bot_b,
    float* __restrict__ beb)
{
  __shared__ __align__(16) unsigned short h1p[18 * 18 * 32]; // conv: padded h1 bf16, swizzled
  __shared__ __align__(16) unsigned short xpad[1304];        // conv: [18][18][4ch] bf16
  __shared__ __align__(16) unsigned short Asm[64 * 64];      // wfuse: 8KB
  __shared__ float red2[2][128];                             // beb
  int bid = blockIdx.x;
  int t = threadIdx.x, l = t & 63, w = t >> 6;
  int lr = l & 15, cg = l >> 4;

  if (bid < 12288) {
    int grp = bid / 3, rem3 = bid - grp * 3;
    if (rem3 < 2) {                    // ---- conv (r9/r14 proven body), img = grp*2+rem3 ----
      int img = grp * 2 + rem3;
      for (int i = t; i < 1296; i += 256) ((uint4*)h1p)[i] = uint4{0, 0, 0, 0};
      if (t < 163) ((uint4*)xpad)[t] = uint4{0, 0, 0, 0};

      bf16x8 w1a[4];
#pragma unroll
      for (int i = 0; i < 4; ++i) w1a[i] = *(const bf16x8*)(w1p + ((size_t)i * 64 + l) * 8);
      f32x4 b1v0 = *(const f32x4*)(b1 + cg * 4);
      f32x4 b1v1 = *(const f32x4*)(b1 + 16 + cg * 4);

      __syncthreads();
      {
        const float* xs = x + ((size_t)img * 256 + t) * 3;
        float v0 = xs[0], v1 = xs[1], v2 = xs[2];
        uint2 pk;
        pk.x = cvtpk(v0, v1);
        pk.y = cvtpk(v2, 0.f);
        int py = t >> 4, px = t & 15;
        *(uint2*)&xpad[((py + 1) * 18 + (px + 1)) * 4] = pk;
      }
      __syncthreads();

      for (int oi = 0; oi < 4; ++oi) {
        int oy = w + oi * 4;
        if (oy > 14) break;
        f32x4 a0 = b1v0, a1 = b1v1;
#pragma unroll
        for (int kt2 = 0; kt2 < 2; ++kt2) {
          int row = oy + kt2 * 2 + (cg >> 1);
          int c0 = lr + (cg & 1) * 2;
          union { bf16x4 h[2]; bf16x8 v; } u;
          u.h[0] = *(const bf16x4*)&xpad[(row * 18 + c0) * 4];
          u.h[1] = *(const bf16x4*)&xpad[(row * 18 + c0 + 1) * 4];
          a0 = __builtin_amdgcn_mfma_f32_16x16x32_bf16(w1a[kt2 * 2 + 0], u.v, a0, 0, 0, 0);
          a1 = __builtin_amdgcn_mfma_f32_16x16x32_bf16(w1a[kt2 * 2 + 1], u.v, a1, 0, 0, 0);
        }
        if (lr < 15) {
          int row2 = oy + 2, col2 = lr + 2;
          int h = (((row2 >> 1) & 1) << 2) | ((col2 >> 1) & 3);
          int pixbase = (row2 * 18 + col2) * 32;
          int off = (cg & 1) * 4;
          {
            uint2 pk;
            pk.x = cvtpk(fmaxf(a0[0], 0.f), fmaxf(a0[1], 0.f));
            pk.y = cvtpk(fmaxf(a0[2], 0.f), fmaxf(a0[3], 0.f));
            int g8 = (cg >> 1);
            *(uint2*)&h1p[pixbase + ((g8 ^ h) << 3) + off] = pk;
          }
          {
            uint2 pk;
            pk.x = cvtpk(fmaxf(a1[0], 0.f), fmaxf(a1[1], 0.f));
            pk.y = cvtpk(fmaxf(a1[2], 0.f), fmaxf(a1[3], 0.f));
            int g8 = 2 + (cg >> 1);
            *(uint2*)&h1p[pixbase + ((g8 ^ h) << 3) + off] = pk;
          }
        }
      }
      __syncthreads();

      int wm = w >> 1, wn = w & 1;
      int ox2 = lr & 7;
      f32x4 acc2[2][2] = {};
#pragma unroll
      for (int q = 0; q < 4; ++q) {
        int kyh = q >> 1, kxh = q & 1;
        bf16x8 bq[2][4];
#pragma unroll
        for (int ntl = 0; ntl < 2; ++ntl)
#pragma unroll
          for (int kk = 0; kk < 4; ++kk) {
            int kt = (2 * kyh + (kk >> 1)) * 4 + 2 * kxh + (kk & 1);
            bq[ntl][kk] = *(const bf16x8*)(w2p + ((size_t)(kt * 4 + wn * 2 + ntl) * 64 + l) * 8);
          }
#pragma unroll
        for (int mtl = 0; mtl < 2; ++mtl) {
          int oy2 = (wm * 2 + mtl) * 2 + (lr >> 3);
          int ry = oy2 + kyh, rx = ox2 + kxh;
          int h = ((ry & 1) << 2) | (rx & 3);
          const unsigned short* ap = h1p + ((ry * 2) * 18 + rx * 2) * 32 + ((cg ^ h) << 3);
          bf16x8 a00 = *(const bf16x8*)(ap);
          bf16x8 a01 = *(const bf16x8*)(ap + 32);
          bf16x8 a10 = *(const bf16x8*)(ap + 576);
          bf16x8 a11 = *(const bf16x8*)(ap + 608);
#pragma unroll
          for (int ntl = 0; ntl < 2; ++ntl) {
            acc2[mtl][ntl] = __builtin_amdgcn_mfma_f32_16x16x32_bf16(a00, bq[ntl][0], acc2[mtl][ntl], 0, 0, 0);
            acc2[mtl][ntl] = __builtin_amdgcn_mfma_f32_16x16x32_bf16(a01, bq[ntl][1], acc2[mtl][ntl], 0, 0, 0);
            acc2[mtl][ntl] = __builtin_amdgcn_mfma_f32_16x16x32_bf16(a10, bq[ntl][2], acc2[mtl][ntl], 0, 0, 0);
            acc2[mtl][ntl] = __builtin_amdgcn_mfma_f32_16x16x32_bf16(a11, bq[ntl][3], acc2[mtl][ntl], 0, 0, 0);
          }
        }
      }
      unsigned short* fr = flat + (size_t)img * 4096;
#pragma unroll
      for (int ntl = 0; ntl < 2; ++ntl) {
        int co = (wn * 2 + ntl) * 16 + lr;
        float bias2 = b2[co];
#pragma unroll
        for (int mtl = 0; mtl < 2; ++mtl)
#pragma unroll
          for (int r = 0; r < 4; ++r) {
            int pix = (wm * 2 + mtl) * 16 + cg * 4 + r;
            fr[pix * 64 + co] = f2bf(fmaxf(acc2[mtl][ntl][r] + bias2, 0.f));
          }
      }
    } else {                           // ---- trep pack block, gl base = grp ----
      int tid = grp * 256 + t;         // 16384 groups x 64 lanes
      int gl = tid >> 6, l2 = tid & 63;
      int lr2 = l2 & 15, chunk = l2 >> 4;
      int tk = gl >> 10, rem = gl & 1023;
      int kt = rem >> 3, nt = rem & 7;
      const float* src = trep_w + (size_t)tk * 4096 * 128;
      int k0 = kt * 32 + chunk * 8, n = nt * 16 + lr2;
      unsigned short v[8];
#pragma unroll
      for (int e = 0; e < 8; ++e) v[e] = f2bf(src[(size_t)(k0 + e) * 128 + n]);
      uint4 pk = { (unsigned)v[0] | ((unsigned)v[1] << 16), (unsigned)v[2] | ((unsigned)v[3] << 16),
                   (unsigned)v[4] | ((unsigned)v[5] << 16), (unsigned)v[6] | ((unsigned)v[7] << 16) };
      *(uint4*)(trepp + (size_t)tk * 524288 + ((size_t)rem * 64 + l2) * 8) = pk;
    }
  } else if (bid < 12416) {            // ---- wfuse: W_eb = exp_w @ bot_w -> B-frag ----
    int wb = bid - 12288;
    int nb = wb & 1, mb = wb >> 1;     // mb 0..63
    int wm = w >> 1, wn = w & 1;
    int cig = l >> 4;
    f32x4 acc[2][2] = {};
    for (int ktb = 0; ktb < 8; ++ktb) {
      __syncthreads();
#pragma unroll
      for (int jj = 0; jj < 2; ++jj) {
        int q = w * 128 + jj * 64 + l;
        int row = q >> 3, p = q & 7;
        const unsigned short* g = expb + (size_t)(mb * 64 + row) * 512 + ktb * 64 + ((p ^ (row & 7)) * 8);
        gl_lds16(g, (char*)Asm + (w * 128 + jj * 64) * 16);
      }
      __syncthreads();
#pragma unroll
      for (int k32 = 0; k32 < 2; ++k32) {
        bf16x8 af[2];
#pragma unroll
        for (int mf = 0; mf < 2; ++mf) {
          int row = wm * 32 + mf * 16 + lr;
          int c = k32 * 4 + cig;
          af[mf] = *(const bf16x8*)(Asm + row * 64 + ((c ^ (row & 7)) * 8));
        }
#pragma unroll
        for (int nf = 0; nf < 2; ++nf) {
          int ntg = nb * 4 + wn * 2 + nf;
          bf16x8 bf = *(const bf16x8*)(botp + ((size_t)((ktb * 2 + k32) * 8 + ntg) * 64 + l) * 8);
#pragma unroll
          for (int mf = 0; mf < 2; ++mf)
            acc[mf][nf] = __builtin_amdgcn_mfma_f32_16x16x32_bf16(af[mf], bf, acc[mf][nf], 0, 0, 0);
        }
      }
    }
#pragma unroll
    for (int nf = 0; nf < 2; ++nf) {
      int n = nb * 64 + (wn * 2 + nf) * 16 + lr;
#pragma unroll
      for (int mf = 0; mf < 2; ++mf) {
        int rowb = mb * 64 + wm * 32 + mf * 16 + (l >> 4) * 4;
#pragma unroll
        for (int r = 0; r < 4; ++r) {
          int row = rowb + r;               // K-index of W_eb
          int ktn = row >> 5, rr = row & 31;
          int l2 = (rr >> 3) * 16 + (n & 15);
          webp[((size_t)(ktn * 8 + (n >> 4)) * 64 + l2) * 8 + (rr & 7)] = f2bf(acc[mf][nf][r]);
        }
      }
    }
  } else {                             // ---- beb = exp_b @ bot_w + bot_b ----
    int n = t & 127, js = t >> 7;      // js in [0,2): j-chunk of 256
    float s = 0.f;
    for (int j = js * 256; j < js * 256 + 256; ++j)
      s += exp_b[j] * bot_w[j * 128 + n];
    red2[js][n] = s;
    __syncthreads();
    if (t < 128) beb[t] = bot_b[t] + (red2[0][t] + red2[1][t]);
  }
}

// ---------------- K-split grouped GEMM, M=128, K-split 4, single-buffer 2-barrier ----------------
// blockIdx: x = m-tile (0..7, 128 rows each), y = task (0..15), z = k-slice (0..3; 1024 K each)
__global__ __launch_bounds__(512) void k_task6(
    const unsigned short* __restrict__ flat, const unsigned short* __restrict__ trepp,
    const unsigned short* __restrict__ webp,
    const int* __restrict__ cnt, const int* __restrict__ offs, const int* __restrict__ perm,
    float* __restrict__ part)
{
  __shared__ __align__(16) unsigned short Asm[128 * 64];   // 16KB, XOR-swizzled
  __shared__ __align__(16) unsigned short Bsm[8192];       // 16KB trep frags
  __shared__ __align__(16) unsigned short Wsm[8192];       // 16KB W_eb frags
  __shared__ int prow[128];
  int t = threadIdx.x, l = t & 63, w = t >> 6;
  int mt = blockIdx.x, task = blockIdx.y, ks = blockIdx.z;
  int count = cnt[task];
  int r0 = mt * 128;
  if (r0 >= count) return;
  int nrows = count - r0; if (nrows > 128) nrows = 128;
  int base = offs[task];
  if (t < 128) { int rr = t < nrows ? t : (nrows - 1); prow[t] = perm[base + r0 + rr]; }
  __syncthreads();
  int lr = l & 15, cig = l >> 4;
  f32x4 atr[8] = {}, ash[8] = {};
  const unsigned short* Bt = trepp + (size_t)task * 524288;

  for (int it = 0; it < 16; ++it) {
    int ktb = ks * 16 + it;
    __syncthreads();
#pragma unroll
    for (int ii = 0; ii < 2; ++ii) {
      int c = ii * 512 + t;
      int row = c >> 3, s = c & 7;
      const unsigned short* g = flat + (size_t)prow[row] * 4096 + ktb * 64 + ((s ^ (row & 7)) * 8);
      gl_lds16(g, (char*)Asm + (ii * 512 + w * 64) * 16);
    }
#pragma unroll
    for (int ii = 0; ii < 2; ++ii) {
      int c = ii * 512 + t;
      gl_lds16(Bt + (size_t)ktb * 8192 + c * 8, (char*)Bsm + (ii * 512 + w * 64) * 16);
      gl_lds16(webp + (size_t)ktb * 8192 + c * 8, (char*)Wsm + (ii * 512 + w * 64) * 16);
    }
    __syncthreads();
    int arow = w * 16 + lr;
#pragma unroll
    for (int k32 = 0; k32 < 2; ++k32) {
      bf16x8 af = *(const bf16x8*)(Asm + arow * 64 + (((k32 * 4 + cig) ^ (arow & 7)) * 8));
      const unsigned short* bs = Bsm + k32 * 4096;
      const unsigned short* ws = Wsm + k32 * 4096;
#pragma unroll
      for (int nf = 0; nf < 8; ++nf) {
        bf16x8 bf = *(const bf16x8*)(bs + (nf * 64 + l) * 8);
        atr[nf] = __builtin_amdgcn_mfma_f32_16x16x32_bf16(af, bf, atr[nf], 0, 0, 0);
        bf16x8 wf = *(const bf16x8*)(ws + (nf * 64 + l) * 8);
        ash[nf] = __builtin_amdgcn_mfma_f32_16x16x32_bf16(af, wf, ash[nf], 0, 0, 0);
      }
    }
  }

  // write fp32 partials: part[ks][base + r0 + r_loc][n(0-127=shared,128-255=trep)]
  size_t gb = (size_t)ks * 8192 + base + r0;
#pragma unroll
  for (int nf = 0; nf < 8; ++nf) {
    int n = nf * 16 + lr;
#pragma unroll
    for (int r = 0; r < 4; ++r) {
      int r_loc = w * 16 + cig * 4 + r;
      if (r_loc < nrows) {
        float* p = part + (gb + r_loc) * 256;
        p[n] = ash[nf][r];
        p[128 + n] = atr[nf][r];
      }
    }
  }
}

// ---------------- epilogue: sum 4 slices, bias+relu, head, scatter ----------------
__global__ __launch_bounds__(256) void k_fin(
    const float* __restrict__ part,
    const int* __restrict__ perm, const int* __restrict__ task,
    const float* __restrict__ trep_b, const float* __restrict__ b_eb,
    const float* __restrict__ thead_w, const float* __restrict__ thead_b,
    float* __restrict__ out)
{
  __shared__ float sm[32 * 260];
  __shared__ int tsk[32], orow[32];
  int t = threadIdx.x;
  int g0 = blockIdx.x * 32;
  if (t < 32) {
    int orig = perm[g0 + t];
    orow[t] = orig;
    tsk[t] = task[orig];
  }
  __syncthreads();
  // phase 1: sum 4 slices, bias+relu -> sm
  for (int i = t; i < 32 * 64; i += 256) {
    int r = i >> 6, c4 = (i & 63) * 4;
    f32x4 s = {};
#pragma unroll
    for (int sl = 0; sl < 4; ++sl)
      s += *(const f32x4*)(part + ((size_t)sl * 8192 + g0 + r) * 256 + c4);
    f32x4 bv;
    if (c4 < 128) bv = *(const f32x4*)(b_eb + c4);
    else bv = *(const f32x4*)(trep_b + tsk[r] * 128 + (c4 - 128));
    s += bv;
    s = f32x4{fmaxf(s[0], 0.f), fmaxf(s[1], 0.f), fmaxf(s[2], 0.f), fmaxf(s[3], 0.f)};
    *(f32x4*)(sm + r * 260 + c4) = s;
  }
  __syncthreads();
  // phase 2: head (128 active threads: 32 rows x 4 actions)
  if (t < 128) {
    int r = t >> 2, a = t & 3;
    int tk = tsk[r];
    const float* thw = thead_w + (size_t)tk * 1024;
    float q = thead_b[tk * 4 + a];
    for (int c = 0; c < 256; ++c) q += sm[r * 260 + c] * thw[c * 4 + a];
    out[(size_t)orow[r] * 4 + a] = q;
  }
}

// ---------------- fallback fused grouped GEMM (small-ws path) ----------------
__global__ __launch_bounds__(256) void k_task2(
    const unsigned short* __restrict__ flat, const unsigned short* __restrict__ trepp,
    const unsigned short* __restrict__ webp,
    const float* __restrict__ trep_b, const float* __restrict__ b_eb,
    const float* __restrict__ thead_w, const float* __restrict__ thead_b,
    const int* __restrict__ cnt, const int* __restrict__ offs, const int* __restrict__ perm,
    float* __restrict__ out)
{
  __shared__ __align__(16) unsigned short Asm[64 * 64];
  __shared__ __align__(16) unsigned short Bsm[2 * 8 * 64 * 8];
  __shared__ __align__(16) unsigned short Wsm[2 * 8 * 64 * 8];
  __shared__ int prow[64];
  int t = threadIdx.x, l = t & 63, w = t >> 6;
  int task = blockIdx.x >> 7, mt = blockIdx.x & 127;
  int count = cnt[task];
  int r0 = mt * 64;
  if (r0 >= count) return;
  int nrows = count - r0; if (nrows > 64) nrows = 64;
  int base = offs[task];
  if (t < 64) { int rr = t < nrows ? t : (nrows - 1); prow[t] = perm[base + r0 + rr]; }
  __syncthreads();
  int lr = l & 15, cig = l >> 4;
  f32x4 atr[8] = {}, ash[8] = {};
  const unsigned short* Bt = trepp + (size_t)task * 524288;

  for (int ktb = 0; ktb < 64; ++ktb) {
    __syncthreads();
#pragma unroll
    for (int ii = 0; ii < 2; ++ii) {
      int c = ii * 256 + w * 64 + l;
      int row = c >> 3, s = c & 7;
      const unsigned short* g = flat + (size_t)prow[row] * 4096 + ktb * 64 + ((s ^ (row & 7)) * 8);
      gl_lds16(g, (char*)Asm + (ii * 256 + w * 64) * 16);
    }
#pragma unroll
    for (int ii = 0; ii < 4; ++ii) {
      int c = ii * 256 + w * 64 + l;
      gl_lds16(Bt + (size_t)ktb * 8192 + c * 8, (char*)Bsm + (ii * 256 + w * 64) * 16);
      gl_lds16(webp + (size_t)ktb * 8192 + c * 8, (char*)Wsm + (ii * 256 + w * 64) * 16);
    }
    __syncthreads();
    int arow = w * 16 + lr;
#pragma unroll
    for (int k32 = 0; k32 < 2; ++k32) {
      bf16x8 af = *(const bf16x8*)(Asm + arow * 64 + (((k32 * 4 + cig) ^ (arow & 7)) * 8));
      const unsigned short* bs = Bsm + k32 * 4096;
      const unsigned short* ws = Wsm + k32 * 4096;
#pragma unroll
      for (int nf = 0; nf < 8; ++nf) {
        bf16x8 bf = *(const bf16x8*)(bs + (nf * 64 + l) * 8);
        atr[nf] = __builtin_amdgcn_mfma_f32_16x16x32_bf16(af, bf, atr[nf], 0, 0, 0);
        bf16x8 wf = *(const bf16x8*)(ws + (nf * 64 + l) * 8);
        ash[nf] = __builtin_amdgcn_mfma_f32_16x16x32_bf16(af, wf, ash[nf], 0, 0, 0);
      }
    }
  }

  const float* thw = thead_w + (size_t)task * 1024;
  f32x4 qp[4] = {};
#pragma unroll
  for (int nf = 0; nf < 8; ++nf) {
    int n = nf * 16 + lr;
    float tb = trep_b[task * 128 + n];
    float bb = b_eb[n];
    f32x4 wsh = *(const f32x4*)(thw + n * 4);
    f32x4 wtr = *(const f32x4*)(thw + (128 + n) * 4);
#pragma unroll
    for (int r = 0; r < 4; ++r) {
      float sh = fmaxf(ash[nf][r] + bb, 0.f);
      float tr = fmaxf(atr[nf][r] + tb, 0.f);
      qp[r] += sh * wsh + tr * wtr;
    }
  }
#pragma unroll
  for (int m = 1; m < 16; m <<= 1)
#pragma unroll
    for (int r = 0; r < 4; ++r)
#pragma unroll
      for (int c2 = 0; c2 < 4; ++c2)
        qp[r][c2] += __shfl_xor(qp[r][c2], m, 64);

  if (lr < 4) {
    int rloc = w * 16 + cig * 4 + lr;
    if (rloc < nrows) {
      f32x4 q = qp[lr];
      f32x4 tb4 = *(const f32x4*)(thead_b + task * 4);
      q += tb4;
      *(f32x4*)(out + (size_t)prow[rloc] * 4) = q;
    }
  }
}

// ---------------- launcher ----------------
extern "C" void kernel_launch(void* const* d_in, const int* in_sizes, int n_in,
                              void* d_out, int out_size, void* d_ws, size_t ws_size,
                              hipStream_t stream)
{
  const float* x    = (const float*)d_in[0];
  const int*   task = (const int*)d_in[1];
  const float* c1w  = (const float*)d_in[2];
  const float* c1b  = (const float*)d_in[3];
  const float* c2w  = (const float*)d_in[4];
  const float* c2b  = (const float*)d_in[5];
  const float* expw = (const float*)d_in[6];
  const float* expb_bias = (const float*)d_in[7];
  const float* botw = (const float*)d_in[8];
  const float* botb = (const float*)d_in[9];
  const float* trw  = (const float*)d_in[10];
  const float* trb  = (const float*)d_in[11];
  const float* thw  = (const float*)d_in[12];
  const float* thb  = (const float*)d_in[13];
  float* out = (float*)d_out;
  char* ws = (char*)d_ws;

  unsigned short* flat  = (unsigned short*)(ws + OFF_FLAT);
  unsigned short* trepp = (unsigned short*)(ws + OFF_TREPP);
  unsigned short* w1p   = (unsigned short*)(ws + OFF_W1P);
  unsigned short* w2p   = (unsigned short*)(ws + OFF_W2P);
  unsigned short* botp  = (unsigned short*)(ws + OFF_BOTP);
  unsigned short* expb  = (unsigned short*)(ws + OFF_EXPB);
  unsigned short* webp  = (unsigned short*)(ws + OFF_WEBP);
  float* beb  = (float*)(ws + OFF_BEB);
  int* cnt    = (int*)(ws + OFF_CNT);
  int* offs   = (int*)(ws + OFF_OFFS);
  int* perm   = (int*)(ws + OFF_PERM);
  float* part = (float*)(ws + OFF_PART);

  k_prep<<<1074, 256, 0, stream>>>(c2w, botw, c1w, expw, task,
                                   w2p, botp, w1p, expb, cnt, offs, perm);
  k_convx<<<12417, 256, 0, stream>>>(x, w1p, c1b, w2p, c2b, flat,
                                     trw, trepp,
                                     expb, botp, webp, expb_bias, botw, botb, beb);
  if (ws_size >= WS_NEEDED) {
    k_task6<<<dim3(8, 16, 4), 512, 0, stream>>>(flat, trepp, webp, cnt, offs, perm, part);
    k_fin<<<256, 256, 0, stream>>>(part, perm, task, trb, beb, thw, thb, out);
  } else {
    k_task2<<<2048, 256, 0, stream>>>(flat, trepp, webp, trb, beb, thw, thb, cnt, offs, perm, out);
  }
}